// Round 14
// baseline (44.905 us; speedup 1.0000x reference)
//
#include <hip/hip_runtime.h>

// PQC: h = tanh(x @ W^T) * scale; 8-qubit circuit via exact transfer-matrix
// contraction (CNOT staircase = prefix-XOR => MPS bond dim 2 per staircase;
// <Z_i> = 1D chain contraction, symmetry-reduced 2x3 state).
// R14 = R13 (38.1us: LDS-W + unroll-2 + DPP row reduce) with ONE change:
// the GEMM inner product runs on packed v_pk_fma_f32 (float2 ext-vectors,
// __builtin_elementwise_fma) -> GEMM VALU issue halved (3072->1536 cy/wave).
// launch_bounds(256,4) pins VGPR<=128 so residency stays 4 waves/SIMD.

typedef float v2f __attribute__((ext_vector_type(2)));

__device__ __forceinline__ float fast_tanh(float v) {
    float e = __expf(2.0f * v);
    return 1.0f - 2.0f / (e + 1.0f);   // exact at +/-inf overflow
}

template<int CTRL>
__device__ __forceinline__ float dpp_rotadd(float v) {
    int s = __builtin_bit_cast(int, v);
    int r = __builtin_amdgcn_update_dpp(s, s, CTRL, 0xf, 0xf, false);
    return v + __builtin_bit_cast(float, r);
}

__device__ __forceinline__ float row16_sum(float v) {
    v = dpp_rotadd<0x121>(v);   // row_ror:1
    v = dpp_rotadd<0x122>(v);   // row_ror:2
    v = dpp_rotadd<0x124>(v);   // row_ror:4
    v = dpp_rotadd<0x128>(v);   // row_ror:8
    return v;
}

__global__ __launch_bounds__(256, 4)
void pqc_kernel(const float* __restrict__ x,
                const float* __restrict__ Wp,
                const float* __restrict__ scalep,
                const float* __restrict__ wts,
                float* __restrict__ out)
{
    __shared__ float hb[64][8];   // per-block projection results (pre-tanh)
    __shared__ float Wl[6144];    // 8 x 768 W tile, 24 KB

    const int tid  = threadIdx.x;
    const int lane = tid & 63;
    const int wave = tid >> 6;            // 0..3
    const int b0   = blockIdx.x * 64;

    const int s4  = lane >> 4;            // 0..3  sample sub-group
    const int c16 = lane & 15;            // 0..15 column group

    // ---- stage W into LDS (256 threads x 6 float4) ----
    {
        const float4* Wv4 = reinterpret_cast<const float4*>(Wp);
        float4*       Lv4 = reinterpret_cast<float4*>(Wl);
        #pragma unroll
        for (int k = 0; k < 6; ++k)
            Lv4[tid + k * 256] = Wv4[tid + k * 256];
    }
    __syncthreads();

    // ---------------- projection phase: this wave's 16 samples ----------------
    const int rbase = b0 + wave * 16;
    v2f acc2[4][8];
    #pragma unroll
    for (int p = 0; p < 4; ++p)
        #pragma unroll
        for (int q = 0; q < 8; ++q) acc2[p][q] = (v2f)(0.f);

    #pragma unroll 2
    for (int j = 0; j < 12; ++j) {
        const int col4 = j * 16 + c16;    // float4 index within a 768-float row
        v2f w01[8], w23[8];
        #pragma unroll
        for (int q = 0; q < 8; ++q) {
            const float4 wv = *reinterpret_cast<const float4*>(Wl + q * 768 + col4 * 4);
            w01[q] = (v2f){wv.x, wv.y};
            w23[q] = (v2f){wv.z, wv.w};
        }
        #pragma unroll
        for (int p = 0; p < 4; ++p) {
            const float4 xv = *reinterpret_cast<const float4*>(
                x + (size_t)(rbase + p * 4 + s4) * 768 + col4 * 4);
            const v2f x01 = (v2f){xv.x, xv.y};
            const v2f x23 = (v2f){xv.z, xv.w};
            #pragma unroll
            for (int q = 0; q < 8; ++q) {
                acc2[p][q] = __builtin_elementwise_fma(x01, w01[q], acc2[p][q]);
                acc2[p][q] = __builtin_elementwise_fma(x23, w23[q], acc2[p][q]);
            }
        }
    }

    // horizontal fold + 16-lane DPP rotate-reduce (VALU pipe)
    float acc[4][8];
    #pragma unroll
    for (int p = 0; p < 4; ++p)
        #pragma unroll
        for (int q = 0; q < 8; ++q)
            acc[p][q] = row16_sum(acc2[p][q].x + acc2[p][q].y);

    if (c16 == 0) {
        #pragma unroll
        for (int p = 0; p < 4; ++p) {
            const int srow = wave * 16 + p * 4 + s4;
            #pragma unroll
            for (int q = 0; q < 8; ++q) hb[srow][q] = acc[p][q];
        }
    }
    __syncthreads();

    // ---------------- circuit phase: transfer-matrix, one sample per thread ----
    // Active: lanes 0..15 of each wave -> 64 samples per block, one per thread.
    if (lane < 16) {
        const int sl   = wave * 16 + lane;     // local sample 0..63
        const int samp = b0 + sl;
        const float scl = scalep[0];

        // per-sample single-qubit input amplitudes: f0=cos(phi/2), f1=sin(phi/2)
        // phi folds the data RY and the layer-0 weight RY (both pre-entangler).
        float f0[8], f1[8];
        #pragma unroll
        for (int q = 0; q < 8; ++q) {
            float ang = fast_tanh(hb[sl][q]) * scl + wts[q];
            __sincosf(0.5f * ang, &f1[q], &f0[q]);
        }
        // layer-1 RY params (uniform): G-tables c^2, s^2, c*s
        float c2[8], s2[8], cs[8];
        #pragma unroll
        for (int q = 0; q < 8; ++q) {
            float sw, cw;
            __sincosf(0.5f * wts[8 + q], &sw, &cw);
            c2[q] = cw * cw; s2[q] = sw * sw; cs[q] = cw * sw;
        }

        // state vector over (b, sym(beta,beta~)): [2][3], t: 0=(00),1=(01/10),2=(11)
        // prefix sweep: Lp[q] = L^(q); Lp[0] = e_{b=0,t=0}
        float Lp[9][2][3];
        Lp[0][0][0] = 1.f; Lp[0][0][1] = 0.f; Lp[0][0][2] = 0.f;
        Lp[0][1][0] = 0.f; Lp[0][1][1] = 0.f; Lp[0][1][2] = 0.f;

        #pragma unroll
        for (int q = 0; q < 8; ++q) {
            const float A = f0[q] * f0[q];
            const float B = f0[q] * f1[q];
            const float C = f1[q] * f1[q];
            float u[2][3];
            #pragma unroll
            for (int b = 0; b < 2; ++b) {
                const float v0 = Lp[q][b][0], v1 = Lp[q][b][1], v2 = Lp[q][b][2];
                u[b][0] = A * v0 + 2.f * B * v1 + C * v2;
                u[b][1] = B * v0 + (A + C) * v1 + B * v2;
                u[b][2] = C * v0 + 2.f * B * v1 + A * v2;
            }
            Lp[q+1][0][0] = c2[q] * u[0][0] + s2[q] * u[1][0];
            Lp[q+1][1][0] = s2[q] * u[0][0] + c2[q] * u[1][0];
            const float m = cs[q] * (u[1][1] - u[0][1]);
            Lp[q+1][0][1] = m;
            Lp[q+1][1][1] = -m;
            Lp[q+1][0][2] = s2[q] * u[0][2] + c2[q] * u[1][2];
            Lp[q+1][1][2] = c2[q] * u[0][2] + s2[q] * u[1][2];
        }

        // suffix sweep + signed dots: z_i = <S^(i+1), (+/- on b) L^(i+1)>
        float S[2][3] = {{1.f, 1.f, 1.f}, {1.f, 1.f, 1.f}};
        float z[8];
        #pragma unroll
        for (int i = 7; i >= 0; --i) {
            z[i] = (S[0][0] * Lp[i+1][0][0] + 2.f * S[0][1] * Lp[i+1][0][1] + S[0][2] * Lp[i+1][0][2])
                 - (S[1][0] * Lp[i+1][1][0] + 2.f * S[1][1] * Lp[i+1][1][1] + S[1][2] * Lp[i+1][1][2]);
            if (i > 0) {
                float u[2][3];
                u[0][0] = c2[i] * S[0][0] + s2[i] * S[1][0];
                u[1][0] = s2[i] * S[0][0] + c2[i] * S[1][0];
                const float m = cs[i] * (S[1][1] - S[0][1]);
                u[0][1] = m; u[1][1] = -m;
                u[0][2] = s2[i] * S[0][2] + c2[i] * S[1][2];
                u[1][2] = c2[i] * S[0][2] + s2[i] * S[1][2];
                const float A = f0[i] * f0[i];
                const float B = f0[i] * f1[i];
                const float C = f1[i] * f1[i];
                #pragma unroll
                for (int b = 0; b < 2; ++b) {
                    const float u0 = u[b][0], u1 = u[b][1], u2 = u[b][2];
                    S[b][0] = A * u0 + 2.f * B * u1 + C * u2;
                    S[b][1] = B * u0 + (A + C) * u1 + B * u2;
                    S[b][2] = C * u0 + 2.f * B * u1 + A * u2;
                }
            }
        }

        float4* o = reinterpret_cast<float4*>(out + (size_t)samp * 8);
        o[0] = make_float4(z[0], z[1], z[2], z[3]);
        o[1] = make_float4(z[4], z[5], z[6], z[7]);
    }
}

extern "C" void kernel_launch(void* const* d_in, const int* in_sizes, int n_in,
                              void* d_out, int out_size, void* d_ws, size_t ws_size,
                              hipStream_t stream) {
    const float* x   = (const float*)d_in[0];
    const float* W   = (const float*)d_in[1];
    const float* sc  = (const float*)d_in[2];
    const float* wt  = (const float*)d_in[3];
    float* o         = (float*)d_out;

    const int batch  = in_sizes[0] / 768;     // 65536
    const int blocks = batch / 64;            // 64 samples per block
    pqc_kernel<<<dim3(blocks), dim3(256), 0, stream>>>(x, W, sc, wt, o);
}

// Round 15
// 37.937 us; speedup vs baseline: 1.1837x; 1.1837x over previous
//
#include <hip/hip_runtime.h>

// PQC: h = tanh(x @ W^T) * scale; 8-qubit circuit via exact transfer-matrix
// contraction (CNOT staircase = prefix-XOR => MPS bond dim 2 per staircase;
// <Z_i> = 1D chain contraction, symmetry-reduced 2x3 state).
// R15 = R13 (38.1us: LDS-W + unroll-2 + DPP row reduce) + two cleanups:
//  (a) second __syncthreads removed - hb handoff is wave-private (writer
//      lanes {0,16,32,48} of wave w, readers lanes 0-15 of wave w); same-wave
//      LDS ordering via lgkmcnt suffices, no block rendezvous needed.
//  (b) x base pointers hoisted; j-term is a literal byte offset (<=2816B,
//      folds into global_load's 13-bit imm) - no per-iter 64-bit addr math.

__device__ __forceinline__ float fast_tanh(float v) {
    float e = __expf(2.0f * v);
    return 1.0f - 2.0f / (e + 1.0f);   // exact at +/-inf overflow
}

template<int CTRL>
__device__ __forceinline__ float dpp_rotadd(float v) {
    int s = __builtin_bit_cast(int, v);
    int r = __builtin_amdgcn_update_dpp(s, s, CTRL, 0xf, 0xf, false);
    return v + __builtin_bit_cast(float, r);
}

__device__ __forceinline__ float row16_sum(float v) {
    v = dpp_rotadd<0x121>(v);   // row_ror:1
    v = dpp_rotadd<0x122>(v);   // row_ror:2
    v = dpp_rotadd<0x124>(v);   // row_ror:4
    v = dpp_rotadd<0x128>(v);   // row_ror:8
    return v;
}

__global__ __launch_bounds__(256, 3)
void pqc_kernel(const float* __restrict__ x,
                const float* __restrict__ Wp,
                const float* __restrict__ scalep,
                const float* __restrict__ wts,
                float* __restrict__ out)
{
    __shared__ float hb[64][8];   // per-block projection results (pre-tanh)
    __shared__ float Wl[6144];    // 8 x 768 W tile, 24 KB

    const int tid  = threadIdx.x;
    const int lane = tid & 63;
    const int wave = tid >> 6;            // 0..3
    const int b0   = blockIdx.x * 64;

    const int s4  = lane >> 4;            // 0..3  sample sub-group
    const int c16 = lane & 15;            // 0..15 column group

    // ---- stage W into LDS (256 threads x 6 float4) ----
    {
        const float4* Wv4 = reinterpret_cast<const float4*>(Wp);
        float4*       Lv4 = reinterpret_cast<float4*>(Wl);
        #pragma unroll
        for (int k = 0; k < 6; ++k)
            Lv4[tid + k * 256] = Wv4[tid + k * 256];
    }
    __syncthreads();

    // ---------------- projection phase: this wave's 16 samples ----------------
    const int rbase = b0 + wave * 16;

    // hoisted per-row base pointers: j-loop uses literal offsets only
    const float* xb0 = x + (size_t)(rbase + 0 * 4 + s4) * 768 + c16 * 4;
    const float* xb1 = x + (size_t)(rbase + 1 * 4 + s4) * 768 + c16 * 4;
    const float* xb2 = x + (size_t)(rbase + 2 * 4 + s4) * 768 + c16 * 4;
    const float* xb3 = x + (size_t)(rbase + 3 * 4 + s4) * 768 + c16 * 4;
    const float* wb  = Wl + c16 * 4;

    float acc[4][8];
    #pragma unroll
    for (int p = 0; p < 4; ++p)
        #pragma unroll
        for (int q = 0; q < 8; ++q) acc[p][q] = 0.0f;

    #pragma unroll 2
    for (int j = 0; j < 12; ++j) {
        float4 wv[8];
        #pragma unroll
        for (int q = 0; q < 8; ++q)
            wv[q] = *reinterpret_cast<const float4*>(wb + q * 768 + j * 64);
        #pragma unroll
        for (int p = 0; p < 4; ++p) {
            const float* xb = (p == 0) ? xb0 : (p == 1) ? xb1 : (p == 2) ? xb2 : xb3;
            const float4 xv = *reinterpret_cast<const float4*>(xb + j * 64);
            #pragma unroll
            for (int q = 0; q < 8; ++q) {
                acc[p][q] = fmaf(xv.x, wv[q].x, acc[p][q]);
                acc[p][q] = fmaf(xv.y, wv[q].y, acc[p][q]);
                acc[p][q] = fmaf(xv.z, wv[q].z, acc[p][q]);
                acc[p][q] = fmaf(xv.w, wv[q].w, acc[p][q]);
            }
        }
    }
    // reduce over the 16 column lanes: VALU-pipe DPP rotate-reduce
    #pragma unroll
    for (int p = 0; p < 4; ++p)
        #pragma unroll
        for (int q = 0; q < 8; ++q)
            acc[p][q] = row16_sum(acc[p][q]);

    if (c16 == 0) {
        #pragma unroll
        for (int p = 0; p < 4; ++p) {
            const int srow = wave * 16 + p * 4 + s4;
            #pragma unroll
            for (int q = 0; q < 8; ++q) hb[srow][q] = acc[p][q];
        }
    }
    // NO __syncthreads here: hb rows [wave*16, wave*16+16) are written by
    // lanes {0,16,32,48} of this wave and read only by lanes 0..15 of this
    // wave; same-wave LDS ops are ordered via lgkmcnt.

    // ---------------- circuit phase: transfer-matrix, one sample per thread ----
    // Active: lanes 0..15 of each wave -> 64 samples per block, one per thread.
    if (lane < 16) {
        const int sl   = wave * 16 + lane;     // local sample 0..63
        const int samp = b0 + sl;
        const float scl = scalep[0];

        // per-sample single-qubit input amplitudes: f0=cos(phi/2), f1=sin(phi/2)
        // phi folds the data RY and the layer-0 weight RY (both pre-entangler).
        float f0[8], f1[8];
        #pragma unroll
        for (int q = 0; q < 8; ++q) {
            float ang = fast_tanh(hb[sl][q]) * scl + wts[q];
            __sincosf(0.5f * ang, &f1[q], &f0[q]);
        }
        // layer-1 RY params (uniform): G-tables c^2, s^2, c*s
        float c2[8], s2[8], cs[8];
        #pragma unroll
        for (int q = 0; q < 8; ++q) {
            float sw, cw;
            __sincosf(0.5f * wts[8 + q], &sw, &cw);
            c2[q] = cw * cw; s2[q] = sw * sw; cs[q] = cw * sw;
        }

        // state vector over (b, sym(beta,beta~)): [2][3], t: 0=(00),1=(01/10),2=(11)
        // prefix sweep: Lp[q] = L^(q); Lp[0] = e_{b=0,t=0}
        float Lp[9][2][3];
        Lp[0][0][0] = 1.f; Lp[0][0][1] = 0.f; Lp[0][0][2] = 0.f;
        Lp[0][1][0] = 0.f; Lp[0][1][1] = 0.f; Lp[0][1][2] = 0.f;

        #pragma unroll
        for (int q = 0; q < 8; ++q) {
            const float A = f0[q] * f0[q];
            const float B = f0[q] * f1[q];
            const float C = f1[q] * f1[q];
            float u[2][3];
            #pragma unroll
            for (int b = 0; b < 2; ++b) {
                const float v0 = Lp[q][b][0], v1 = Lp[q][b][1], v2 = Lp[q][b][2];
                u[b][0] = A * v0 + 2.f * B * v1 + C * v2;
                u[b][1] = B * v0 + (A + C) * v1 + B * v2;
                u[b][2] = C * v0 + 2.f * B * v1 + A * v2;
            }
            Lp[q+1][0][0] = c2[q] * u[0][0] + s2[q] * u[1][0];
            Lp[q+1][1][0] = s2[q] * u[0][0] + c2[q] * u[1][0];
            const float m = cs[q] * (u[1][1] - u[0][1]);
            Lp[q+1][0][1] = m;
            Lp[q+1][1][1] = -m;
            Lp[q+1][0][2] = s2[q] * u[0][2] + c2[q] * u[1][2];
            Lp[q+1][1][2] = c2[q] * u[0][2] + s2[q] * u[1][2];
        }

        // suffix sweep + signed dots: z_i = <S^(i+1), (+/- on b) L^(i+1)>
        float S[2][3] = {{1.f, 1.f, 1.f}, {1.f, 1.f, 1.f}};
        float z[8];
        #pragma unroll
        for (int i = 7; i >= 0; --i) {
            z[i] = (S[0][0] * Lp[i+1][0][0] + 2.f * S[0][1] * Lp[i+1][0][1] + S[0][2] * Lp[i+1][0][2])
                 - (S[1][0] * Lp[i+1][1][0] + 2.f * S[1][1] * Lp[i+1][1][1] + S[1][2] * Lp[i+1][1][2]);
            if (i > 0) {
                float u[2][3];
                u[0][0] = c2[i] * S[0][0] + s2[i] * S[1][0];
                u[1][0] = s2[i] * S[0][0] + c2[i] * S[1][0];
                const float m = cs[i] * (S[1][1] - S[0][1]);
                u[0][1] = m; u[1][1] = -m;
                u[0][2] = s2[i] * S[0][2] + c2[i] * S[1][2];
                u[1][2] = c2[i] * S[0][2] + s2[i] * S[1][2];
                const float A = f0[i] * f0[i];
                const float B = f0[i] * f1[i];
                const float C = f1[i] * f1[i];
                #pragma unroll
                for (int b = 0; b < 2; ++b) {
                    const float u0 = u[b][0], u1 = u[b][1], u2 = u[b][2];
                    S[b][0] = A * u0 + 2.f * B * u1 + C * u2;
                    S[b][1] = B * u0 + (A + C) * u1 + B * u2;
                    S[b][2] = C * u0 + 2.f * B * u1 + A * u2;
                }
            }
        }

        float4* o = reinterpret_cast<float4*>(out + (size_t)samp * 8);
        o[0] = make_float4(z[0], z[1], z[2], z[3]);
        o[1] = make_float4(z[4], z[5], z[6], z[7]);
    }
}

extern "C" void kernel_launch(void* const* d_in, const int* in_sizes, int n_in,
                              void* d_out, int out_size, void* d_ws, size_t ws_size,
                              hipStream_t stream) {
    const float* x   = (const float*)d_in[0];
    const float* W   = (const float*)d_in[1];
    const float* sc  = (const float*)d_in[2];
    const float* wt  = (const float*)d_in[3];
    float* o         = (float*)d_out;

    const int batch  = in_sizes[0] / 768;     // 65536
    const int blocks = batch / 64;            // 64 samples per block
    pqc_kernel<<<dim3(blocks), dim3(256), 0, stream>>>(x, W, sc, wt, o);
}